// Round 1
// baseline (1844.984 us; speedup 1.0000x reference)
//
#include <hip/hip_runtime.h>
#include <hip/hip_bf16.h>
#include <math.h>

typedef __bf16 bf16;
typedef __bf16 bf16x4 __attribute__((ext_vector_type(4)));
typedef __bf16 bf16x8 __attribute__((ext_vector_type(8)));
typedef float f32x4 __attribute__((ext_vector_type(4)));

#define D_MODEL 2048
#define NROWS   4096   // B*S
#define NHEADS  16
#define DH      128
#define SEQ     2048

// ---------------------------------------------------------------------------
// QKV projection: y = x @ W + b for W in {Wq,Wk,Wv} (blockIdx.z selects).
// 64x64 output tile per block, 4 waves, each wave does a 16-row slab.
// q -> ws as bf16 [B*H, S, DH]; k,v -> d_out as fp32 [B*H, S, DH].
// ---------------------------------------------------------------------------
__global__ __launch_bounds__(256)
void gemm_qkv_kernel(const float* __restrict__ X,
                     const float* __restrict__ Wq, const float* __restrict__ bq,
                     const float* __restrict__ Wk, const float* __restrict__ bk,
                     const float* __restrict__ Wv, const float* __restrict__ bv,
                     bf16* __restrict__ qout,
                     float* __restrict__ kout,
                     float* __restrict__ vout)
{
    const int z  = blockIdx.z;
    const float* __restrict__ W    = (z == 0) ? Wq : (z == 1) ? Wk : Wv;
    const float* __restrict__ bias = (z == 0) ? bq : (z == 1) ? bk : bv;
    const int bm = blockIdx.y, bn = blockIdx.x;
    const int tid = threadIdx.x;
    const int wave = tid >> 6, lane = tid & 63, quad = lane >> 4, l16 = lane & 15;

    __shared__ bf16 As[64][32];    // A tile, row-major [m][k]
    __shared__ bf16 BsT[64][32];   // B tile transposed [n][k]

    f32x4 acc[4] = {};

    for (int k0 = 0; k0 < D_MODEL; k0 += 32) {
        // stage A: 64x32 fp32 -> bf16 (512 float4, 2 per thread)
#pragma unroll
        for (int i = 0; i < 2; ++i) {
            int idx = tid + i * 256;
            int m = idx >> 3, kq = idx & 7;
            float4 a4 = *(const float4*)&X[(size_t)(bm * 64 + m) * D_MODEL + k0 + kq * 4];
            bf16x4 b4;
            b4[0] = (bf16)a4.x; b4[1] = (bf16)a4.y; b4[2] = (bf16)a4.z; b4[3] = (bf16)a4.w;
            *(bf16x4*)&As[m][kq * 4] = b4;
        }
        // stage B transposed: W[k][n] -> BsT[n][k]
#pragma unroll
        for (int i = 0; i < 2; ++i) {
            int idx = tid + i * 256;
            int k = idx >> 4, nq = idx & 15;
            float4 w4 = *(const float4*)&W[(size_t)(k0 + k) * D_MODEL + bn * 64 + nq * 4];
            BsT[nq * 4 + 0][k] = (bf16)w4.x;
            BsT[nq * 4 + 1][k] = (bf16)w4.y;
            BsT[nq * 4 + 2][k] = (bf16)w4.z;
            BsT[nq * 4 + 3][k] = (bf16)w4.w;
        }
        __syncthreads();

        bf16x8 a = *(const bf16x8*)&As[wave * 16 + l16][quad * 8];
#pragma unroll
        for (int t = 0; t < 4; ++t) {
            bf16x8 b = *(const bf16x8*)&BsT[t * 16 + l16][quad * 8];
            acc[t] = __builtin_amdgcn_mfma_f32_16x16x32_bf16(a, b, acc[t], 0, 0, 0);
        }
        __syncthreads();
    }

#pragma unroll
    for (int t = 0; t < 4; ++t) {
#pragma unroll
        for (int r = 0; r < 4; ++r) {
            int row = bm * 64 + wave * 16 + quad * 4 + r;   // m index (b*S + s)
            int col = bn * 64 + t * 16 + l16;               // n index (h*DH + dh)
            float val = acc[t][r] + bias[col];
            int b = row >> 11, s = row & (SEQ - 1);
            int h = col >> 7, dh = col & (DH - 1);
            size_t off = ((size_t)(b * NHEADS + h) * SEQ + s) * DH + dh;
            if (z == 0)       qout[off] = (bf16)val;
            else if (z == 1)  kout[off] = val;
            else              vout[off] = val;
        }
    }
}

// ---------------------------------------------------------------------------
// Flash attention (causal). One block per (b*h, 64-row q tile). 4 waves,
// each owns 16 q rows. Online softmax; P LDS round-trip to A-layout.
// ctx written bf16 to ws as [B, S, H*DH] = [4096, 2048].
// ---------------------------------------------------------------------------
__global__ __launch_bounds__(256)
void attn_kernel(const bf16* __restrict__ Q,    // [B*H, S, DH] bf16
                 const float* __restrict__ Kf,  // [B*H, S, DH] fp32
                 const float* __restrict__ Vf,  // [B*H, S, DH] fp32
                 bf16* __restrict__ ctx)        // [4096, 2048] bf16
{
    const int qb = blockIdx.x;   // 0..31
    const int bh = blockIdx.y;   // 0..31
    const int tid = threadIdx.x;
    const int wave = tid >> 6, lane = tid & 63, quad = lane >> 4, l16 = lane & 15;

    __shared__ bf16 Qs[64][DH];
    __shared__ bf16 Ks[64][DH];
    __shared__ bf16 Vs[64][DH];
    __shared__ bf16 Ps[4][16][64];

    // load Q tile (1024 x 16B chunks, 4 per thread)
    const bf16* qsrc = Q + ((size_t)bh * SEQ + qb * 64) * DH;
#pragma unroll
    for (int i = 0; i < 4; ++i) {
        int idx = tid + i * 256;
        int row = idx >> 4, c = (idx & 15) * 8;
        *(bf16x8*)&Qs[row][c] = *(const bf16x8*)&qsrc[row * DH + c];
    }

    f32x4 o[8] = {};
    float m_i[4], l_i[4];
#pragma unroll
    for (int r = 0; r < 4; ++r) { m_i[r] = -INFINITY; l_i[r] = 0.f; }

    const float scale = 0.08838834764831845f;  // 1/sqrt(128)
    const float* ksrc = Kf + (size_t)bh * SEQ * DH;
    const float* vsrc = Vf + (size_t)bh * SEQ * DH;

    for (int kb = 0; kb <= qb; ++kb) {
        __syncthreads();  // Vs/Ks safe to overwrite; also covers Q staging on iter 0
        // stage K, V tiles: 64x128 fp32 -> bf16 (2048 float4 each, 8/thread)
#pragma unroll
        for (int i = 0; i < 8; ++i) {
            int idx = tid + i * 256;
            int row = idx >> 5, c = (idx & 31) * 4;
            size_t g = ((size_t)kb * 64 + row) * DH + c;
            float4 k4 = *(const float4*)&ksrc[g];
            bf16x4 kb4;
            kb4[0] = (bf16)k4.x; kb4[1] = (bf16)k4.y; kb4[2] = (bf16)k4.z; kb4[3] = (bf16)k4.w;
            *(bf16x4*)&Ks[row][c] = kb4;
            float4 v4 = *(const float4*)&vsrc[g];
            bf16x4 vb4;
            vb4[0] = (bf16)v4.x; vb4[1] = (bf16)v4.y; vb4[2] = (bf16)v4.z; vb4[3] = (bf16)v4.w;
            *(bf16x4*)&Vs[row][c] = vb4;
        }
        __syncthreads();

        // S = Q K^T for this wave's 16 rows x 64 keys
        f32x4 sc[4] = {};
#pragma unroll
        for (int t = 0; t < 4; ++t) {
#pragma unroll
            for (int d0 = 0; d0 < DH; d0 += 32) {
                bf16x8 a = *(const bf16x8*)&Qs[wave * 16 + l16][d0 + quad * 8];
                bf16x8 b = *(const bf16x8*)&Ks[t * 16 + l16][d0 + quad * 8];
                sc[t] = __builtin_amdgcn_mfma_f32_16x16x32_bf16(a, b, sc[t], 0, 0, 0);
            }
        }

        const bool diag = (kb == qb);
        float pvals[4][4];
#pragma unroll
        for (int r = 0; r < 4; ++r) {
            int qrow = qb * 64 + wave * 16 + quad * 4 + r;
            float mx = -INFINITY;
#pragma unroll
            for (int t = 0; t < 4; ++t) {
                float s = sc[t][r] * scale;
                int kcol = kb * 64 + t * 16 + l16;
                if (diag && kcol > qrow) s = -INFINITY;
                pvals[t][r] = s;
                mx = fmaxf(mx, s);
            }
#pragma unroll
            for (int off = 1; off < 16; off <<= 1)
                mx = fmaxf(mx, __shfl_xor(mx, off, 64));
            float mnew = fmaxf(m_i[r], mx);
            float alpha = expf(m_i[r] - mnew);   // m_i=-inf on first block -> 0
            m_i[r] = mnew;
            float rs = 0.f;
#pragma unroll
            for (int t = 0; t < 4; ++t) {
                float p = expf(pvals[t][r] - mnew);
                pvals[t][r] = p;
                rs += p;
            }
#pragma unroll
            for (int off = 1; off < 16; off <<= 1)
                rs += __shfl_xor(rs, off, 64);
            l_i[r] = l_i[r] * alpha + rs;
#pragma unroll
            for (int dt = 0; dt < 8; ++dt) o[dt][r] *= alpha;
        }

        // P -> LDS (C-layout -> A-layout transform), wave-local region
#pragma unroll
        for (int t = 0; t < 4; ++t)
#pragma unroll
            for (int r = 0; r < 4; ++r)
                Ps[wave][quad * 4 + r][t * 16 + l16] = (bf16)pvals[t][r];

        // O += P @ V
#pragma unroll
        for (int dt = 0; dt < 8; ++dt) {
#pragma unroll
            for (int kk = 0; kk < 64; kk += 32) {
                bf16x8 a = *(const bf16x8*)&Ps[wave][l16][kk + quad * 8];
                bf16x8 b;
#pragma unroll
                for (int j = 0; j < 8; ++j) b[j] = Vs[kk + quad * 8 + j][dt * 16 + l16];
                o[dt] = __builtin_amdgcn_mfma_f32_16x16x32_bf16(a, b, o[dt], 0, 0, 0);
            }
        }
    }

    // epilogue: ctx[b][s][h*DH + d]
    const int b = bh >> 4, h = bh & (NHEADS - 1);
#pragma unroll
    for (int dt = 0; dt < 8; ++dt) {
#pragma unroll
        for (int r = 0; r < 4; ++r) {
            int s = qb * 64 + wave * 16 + quad * 4 + r;
            int d = dt * 16 + l16;
            float val = o[dt][r] / l_i[r];
            ctx[((size_t)(b * SEQ + s)) * D_MODEL + h * DH + d] = (bf16)val;
        }
    }
}

// ---------------------------------------------------------------------------
// Output projection: attn_out = ctx(bf16) @ Wo + bo, fp32 out [4096, 2048]
// ---------------------------------------------------------------------------
__global__ __launch_bounds__(256)
void gemm_out_kernel(const bf16* __restrict__ Xb,
                     const float* __restrict__ W, const float* __restrict__ bias,
                     float* __restrict__ out)
{
    const int bm = blockIdx.y, bn = blockIdx.x;
    const int tid = threadIdx.x;
    const int wave = tid >> 6, lane = tid & 63, quad = lane >> 4, l16 = lane & 15;

    __shared__ bf16 As[64][32];
    __shared__ bf16 BsT[64][32];

    f32x4 acc[4] = {};

    for (int k0 = 0; k0 < D_MODEL; k0 += 32) {
#pragma unroll
        for (int i = 0; i < 2; ++i) {
            int idx = tid + i * 256;
            int m = idx >> 3, kq = idx & 7;
            *(bf16x4*)&As[m][kq * 4] =
                *(const bf16x4*)&Xb[(size_t)(bm * 64 + m) * D_MODEL + k0 + kq * 4];
        }
#pragma unroll
        for (int i = 0; i < 2; ++i) {
            int idx = tid + i * 256;
            int k = idx >> 4, nq = idx & 15;
            float4 w4 = *(const float4*)&W[(size_t)(k0 + k) * D_MODEL + bn * 64 + nq * 4];
            BsT[nq * 4 + 0][k] = (bf16)w4.x;
            BsT[nq * 4 + 1][k] = (bf16)w4.y;
            BsT[nq * 4 + 2][k] = (bf16)w4.z;
            BsT[nq * 4 + 3][k] = (bf16)w4.w;
        }
        __syncthreads();

        bf16x8 a = *(const bf16x8*)&As[wave * 16 + l16][quad * 8];
#pragma unroll
        for (int t = 0; t < 4; ++t) {
            bf16x8 b = *(const bf16x8*)&BsT[t * 16 + l16][quad * 8];
            acc[t] = __builtin_amdgcn_mfma_f32_16x16x32_bf16(a, b, acc[t], 0, 0, 0);
        }
        __syncthreads();
    }

#pragma unroll
    for (int t = 0; t < 4; ++t) {
#pragma unroll
        for (int r = 0; r < 4; ++r) {
            int row = bm * 64 + wave * 16 + quad * 4 + r;
            int col = bn * 64 + t * 16 + l16;
            out[(size_t)row * D_MODEL + col] = acc[t][r] + bias[col];
        }
    }
}

// ---------------------------------------------------------------------------
// Residual + LayerNorm: one block per row (4096 rows, 2048 cols)
// ---------------------------------------------------------------------------
__global__ __launch_bounds__(256)
void ln_kernel(const float* __restrict__ attn, const float* __restrict__ x,
               const float* __restrict__ gamma, const float* __restrict__ beta,
               float* __restrict__ ln)
{
    const int row = blockIdx.x;
    const int tid = threadIdx.x;
    const int wave = tid >> 6, lane = tid & 63;
    const float* a  = attn + (size_t)row * D_MODEL;
    const float* xr = x    + (size_t)row * D_MODEL;

    float4 y4[2];
    float sum = 0.f, sumsq = 0.f;
#pragma unroll
    for (int i = 0; i < 2; ++i) {
        int c = (tid + i * 256) * 4;
        float4 av = *(const float4*)&a[c];
        float4 xv = *(const float4*)&xr[c];
        float4 y;
        y.x = av.x + xv.x; y.y = av.y + xv.y; y.z = av.z + xv.z; y.w = av.w + xv.w;
        y4[i] = y;
        sum   += y.x + y.y + y.z + y.w;
        sumsq += y.x * y.x + y.y * y.y + y.z * y.z + y.w * y.w;
    }
#pragma unroll
    for (int off = 1; off < 64; off <<= 1) {
        sum   += __shfl_xor(sum, off, 64);
        sumsq += __shfl_xor(sumsq, off, 64);
    }
    __shared__ float rsum[4], rsumsq[4];
    if (lane == 0) { rsum[wave] = sum; rsumsq[wave] = sumsq; }
    __syncthreads();
    float tot = 0.f, tot2 = 0.f;
#pragma unroll
    for (int i = 0; i < 4; ++i) { tot += rsum[i]; tot2 += rsumsq[i]; }
    const float mu  = tot * (1.0f / D_MODEL);
    const float var = tot2 * (1.0f / D_MODEL) - mu * mu;
    const float rstd = rsqrtf(var + 1e-5f);

#pragma unroll
    for (int i = 0; i < 2; ++i) {
        int c = (tid + i * 256) * 4;
        float4 gv = *(const float4*)&gamma[c];
        float4 bv = *(const float4*)&beta[c];
        float4 y = y4[i];
        float4 r;
        r.x = gv.x * (y.x - mu) * rstd + bv.x;
        r.y = gv.y * (y.y - mu) * rstd + bv.y;
        r.z = gv.z * (y.z - mu) * rstd + bv.z;
        r.w = gv.w * (y.w - mu) * rstd + bv.w;
        *(float4*)&ln[(size_t)row * D_MODEL + c] = r;
    }
}

// ---------------------------------------------------------------------------
extern "C" void kernel_launch(void* const* d_in, const int* in_sizes, int n_in,
                              void* d_out, int out_size, void* d_ws, size_t ws_size,
                              hipStream_t stream)
{
    const float* x     = (const float*)d_in[0];
    const float* Wq    = (const float*)d_in[1];
    const float* bq    = (const float*)d_in[2];
    const float* Wk    = (const float*)d_in[3];
    const float* bk    = (const float*)d_in[4];
    const float* Wv    = (const float*)d_in[5];
    const float* bv    = (const float*)d_in[6];
    const float* Wo    = (const float*)d_in[7];
    const float* bo    = (const float*)d_in[8];
    const float* gamma = (const float*)d_in[9];
    const float* beta  = (const float*)d_in[10];

    float* out      = (float*)d_out;
    float* ln       = out;                 // [B,S,D]
    float* attn_out = out + 8388608;       // [B,S,D]
    float* kout     = out + 16777216;      // [B,H,S,Dh]
    float* vout     = out + 25165824;      // [B,H,S,Dh]

    bf16* qws   = (bf16*)d_ws;             // [B*H, S, DH] bf16
    bf16* ctxws = (bf16*)d_ws + 8388608;   // [4096, 2048] bf16

    dim3 g1(32, 64, 3);
    gemm_qkv_kernel<<<g1, 256, 0, stream>>>(x, Wq, bq, Wk, bk, Wv, bv, qws, kout, vout);
    dim3 g2(32, 32);
    attn_kernel<<<g2, 256, 0, stream>>>(qws, kout, vout, ctxws);
    dim3 g3(32, 64);
    gemm_out_kernel<<<g3, 256, 0, stream>>>(ctxws, Wo, bo, attn_out);
    ln_kernel<<<4096, 256, 0, stream>>>(attn_out, x, gamma, beta, ln);
}

// Round 2
// 754.066 us; speedup vs baseline: 2.4467x; 2.4467x over previous
//
#include <hip/hip_runtime.h>
#include <hip/hip_bf16.h>
#include <math.h>
#include <stdint.h>

typedef __bf16 bf16;
typedef __bf16 bf16x4 __attribute__((ext_vector_type(4)));
typedef __bf16 bf16x8 __attribute__((ext_vector_type(8)));
typedef float f32x4 __attribute__((ext_vector_type(4)));

#define D_MODEL 2048
#define SEQ     2048
#define NHEADS  16
#define DH      128

// async 16B global -> LDS (wave-uniform LDS base + lane*16)
__device__ __forceinline__ void async_copy16(const bf16* g, bf16* l) {
    typedef const unsigned int __attribute__((address_space(1))) gu32;
    typedef unsigned int __attribute__((address_space(3))) lu32;
    __builtin_amdgcn_global_load_lds((gu32*)g, (lu32*)(unsigned int)(unsigned long long)(l),
                                     16, 0, 0);
}

// ---------------------------------------------------------------------------
// Pre-pass: x fp32 -> bf16 (row-major, unchanged layout)
// ---------------------------------------------------------------------------
__global__ __launch_bounds__(256)
void convert_x_kernel(const float* __restrict__ x, bf16* __restrict__ xb)
{
    int i = blockIdx.x * 256 + threadIdx.x;   // 2M float4 chunks
    float4 v = ((const float4*)x)[i];
    bf16x4 o;
    o[0] = (bf16)v.x; o[1] = (bf16)v.y; o[2] = (bf16)v.z; o[3] = (bf16)v.w;
    ((bf16x4*)xb)[i] = o;
}

// ---------------------------------------------------------------------------
// Pre-pass: W [k][n] fp32 -> WT [n][k] bf16, z selects Wq/Wk/Wv/Wo
// ---------------------------------------------------------------------------
__global__ __launch_bounds__(256)
void transpose_w_kernel(const float* __restrict__ Wq, const float* __restrict__ Wk,
                        const float* __restrict__ Wv, const float* __restrict__ Wo,
                        bf16* __restrict__ WTbase)
{
    const int z = blockIdx.z;
    const float* __restrict__ W = (z == 0) ? Wq : (z == 1) ? Wk : (z == 2) ? Wv : Wo;
    bf16* __restrict__ Wt = WTbase + (size_t)z * (D_MODEL * D_MODEL);
    const int n0 = blockIdx.x * 64, k0 = blockIdx.y * 64;
    const int tid = threadIdx.x;
    __shared__ bf16 Tl[64][68];   // [n][k]

#pragma unroll
    for (int i = 0; i < 4; ++i) {
        int idx = tid + i * 256;
        int kr = idx >> 4, nc = (idx & 15) * 4;
        float4 w = *(const float4*)&W[(size_t)(k0 + kr) * D_MODEL + n0 + nc];
        Tl[nc + 0][kr] = (bf16)w.x;
        Tl[nc + 1][kr] = (bf16)w.y;
        Tl[nc + 2][kr] = (bf16)w.z;
        Tl[nc + 3][kr] = (bf16)w.w;
    }
    __syncthreads();
#pragma unroll
    for (int i = 0; i < 4; ++i) {
        int idx = tid + i * 256;
        int nr = idx >> 4, kc = (idx & 15) * 4;
        *(bf16x4*)&Wt[(size_t)(n0 + nr) * D_MODEL + k0 + kc] = *(const bf16x4*)&Tl[nr][kc];
    }
}

// ---------------------------------------------------------------------------
// Pre-pass (after qkv): vout fp32 [bh][s][128] -> vT bf16 [bh][128][s]
// ---------------------------------------------------------------------------
__global__ __launch_bounds__(256)
void transpose_v_kernel(const float* __restrict__ V, bf16* __restrict__ Vt)
{
    const int s0 = blockIdx.x * 64, d0 = blockIdx.y * 64, bh = blockIdx.z;
    const float* __restrict__ Vb = V + (size_t)bh * SEQ * DH;
    bf16* __restrict__ Vtb = Vt + (size_t)bh * DH * SEQ;
    const int tid = threadIdx.x;
    __shared__ bf16 Tl[64][68];   // [d][s]

#pragma unroll
    for (int i = 0; i < 4; ++i) {
        int idx = tid + i * 256;
        int sr = idx >> 4, dc = (idx & 15) * 4;
        float4 v = *(const float4*)&Vb[(size_t)(s0 + sr) * DH + d0 + dc];
        Tl[dc + 0][sr] = (bf16)v.x;
        Tl[dc + 1][sr] = (bf16)v.y;
        Tl[dc + 2][sr] = (bf16)v.z;
        Tl[dc + 3][sr] = (bf16)v.w;
    }
    __syncthreads();
#pragma unroll
    for (int i = 0; i < 4; ++i) {
        int idx = tid + i * 256;
        int dr = idx >> 4, sc = (idx & 15) * 4;
        *(bf16x4*)&Vtb[(size_t)(d0 + dr) * SEQ + s0 + sc] = *(const bf16x4*)&Tl[dr][sc];
    }
}

// ---------------------------------------------------------------------------
// Core 128x128 bf16 GEMM (BK=64, global_load_lds, fragment-order LDS layout).
// A [M][2048] bf16 row-major, Bt [N][2048] bf16 row-major ([n][k]).
// Fills acc[t][t2] (m-tile t, n-tile t2) for this wave.
// ---------------------------------------------------------------------------
__device__ __forceinline__ void gemm128_core(const bf16* __restrict__ A,
                                             const bf16* __restrict__ Bt,
                                             int bm, int bn,
                                             int wave, int lane,
                                             bf16* As, bf16* Bs,
                                             f32x4 acc[4][4])
{
    const int l16 = lane & 15, quad = lane >> 4;
    const int wave_m = wave >> 1, wave_n = wave & 1;

    for (int k0 = 0; k0 < D_MODEL; k0 += 64) {
        // stage: wave handles rounds j = wave*4 .. wave*4+3 for both tiles.
        // round j: mt = j>>1 (16-row group), kk = j&1 (32-wide k half)
#pragma unroll
        for (int jj = 0; jj < 4; ++jj) {
            int j = wave * 4 + jj;
            int mt = j >> 1, kk = j & 1;
            int col = k0 + kk * 32 + quad * 8;
            const bf16* ga = &A[(size_t)(bm * 128 + mt * 16 + l16) * D_MODEL + col];
            async_copy16(ga, &As[j * 512]);
            const bf16* gb = &Bt[(size_t)(bn * 128 + mt * 16 + l16) * D_MODEL + col];
            async_copy16(gb, &Bs[j * 512]);
        }
        __syncthreads();
#pragma unroll
        for (int kk = 0; kk < 2; ++kk) {
            bf16x8 a[4], b[4];
#pragma unroll
            for (int t = 0; t < 4; ++t) {
                a[t] = *(const bf16x8*)&As[(((wave_m * 4 + t) * 2 + kk) * 64 + lane) * 8];
                b[t] = *(const bf16x8*)&Bs[(((wave_n * 4 + t) * 2 + kk) * 64 + lane) * 8];
            }
#pragma unroll
            for (int t = 0; t < 4; ++t)
#pragma unroll
                for (int t2 = 0; t2 < 4; ++t2)
                    acc[t][t2] = __builtin_amdgcn_mfma_f32_16x16x32_bf16(a[t], b[t2], acc[t][t2], 0, 0, 0);
        }
        __syncthreads();
    }
}

// ---------------------------------------------------------------------------
// QKV projection GEMM. z selects weight. Writes:
//   z=0: q bf16 [bh][s][dh] (ws)
//   z=1: k fp32 [bh][s][dh] (d_out) + bf16 copy (ws)
//   z=2: v fp32 [bh][s][dh] (d_out)
// ---------------------------------------------------------------------------
__global__ __launch_bounds__(256)
void gemm_qkv_kernel(const bf16* __restrict__ A, const bf16* __restrict__ WT,
                     const float* __restrict__ bq, const float* __restrict__ bk,
                     const float* __restrict__ bv,
                     bf16* __restrict__ qout, float* __restrict__ kout,
                     bf16* __restrict__ kb16, float* __restrict__ vout)
{
    const int z = blockIdx.z;
    const bf16* __restrict__ Bt = WT + (size_t)z * (D_MODEL * D_MODEL);
    const float* __restrict__ bias = (z == 0) ? bq : (z == 1) ? bk : bv;
    const int bm = blockIdx.y, bn = blockIdx.x;
    const int tid = threadIdx.x;
    const int wave = tid >> 6, lane = tid & 63, quad = lane >> 4, l16 = lane & 15;
    const int wave_m = wave >> 1, wave_n = wave & 1;

    __shared__ bf16 As[8192];
    __shared__ bf16 Bs[8192];
    f32x4 acc[4][4] = {};

    gemm128_core(A, Bt, bm, bn, wave, lane, As, Bs, acc);

#pragma unroll
    for (int t = 0; t < 4; ++t) {
#pragma unroll
        for (int t2 = 0; t2 < 4; ++t2) {
#pragma unroll
            for (int r = 0; r < 4; ++r) {
                int m = bm * 128 + wave_m * 64 + t * 16 + quad * 4 + r;
                int n = bn * 128 + wave_n * 64 + t2 * 16 + l16;
                float val = acc[t][t2][r] + bias[n];
                int b = m >> 11, s = m & (SEQ - 1);
                int h = n >> 7, dh = n & (DH - 1);
                size_t off = ((size_t)(b * NHEADS + h) * SEQ + s) * DH + dh;
                if (z == 0) {
                    qout[off] = (bf16)val;
                } else if (z == 1) {
                    kout[off] = val;
                    kb16[off] = (bf16)val;
                } else {
                    vout[off] = val;
                }
            }
        }
    }
}

// ---------------------------------------------------------------------------
// Output projection GEMM: attn_out = ctx @ Wo + bo (fp32 out [4096][2048])
// ---------------------------------------------------------------------------
__global__ __launch_bounds__(256)
void gemm_out_kernel(const bf16* __restrict__ A, const bf16* __restrict__ Bt,
                     const float* __restrict__ bias, float* __restrict__ out)
{
    const int bm = blockIdx.y, bn = blockIdx.x;
    const int tid = threadIdx.x;
    const int wave = tid >> 6, lane = tid & 63, quad = lane >> 4, l16 = lane & 15;
    const int wave_m = wave >> 1, wave_n = wave & 1;

    __shared__ bf16 As[8192];
    __shared__ bf16 Bs[8192];
    f32x4 acc[4][4] = {};

    gemm128_core(A, Bt, bm, bn, wave, lane, As, Bs, acc);

#pragma unroll
    for (int t = 0; t < 4; ++t) {
#pragma unroll
        for (int t2 = 0; t2 < 4; ++t2) {
#pragma unroll
            for (int r = 0; r < 4; ++r) {
                int m = bm * 128 + wave_m * 64 + t * 16 + quad * 4 + r;
                int n = bn * 128 + wave_n * 64 + t2 * 16 + l16;
                out[(size_t)m * D_MODEL + n] = acc[t][t2][r] + bias[n];
            }
        }
    }
}

// ---------------------------------------------------------------------------
// Flash attention (causal). One block per (64-row q tile, bh).
// Q,K bf16 [bh][s][128]; Vt bf16 [bh][128][s]; ctx bf16 [b][s][h*128+d].
// LDS strides padded to 16B-aligned, stride/4 mod 32 == 12 (2-way conflicts).
// ---------------------------------------------------------------------------
#define QKPAD 152   // 64..127 used; 152*2=304B=19*16B; 76 dwords % 32 = 12
#define VPAD   88   // 64 used;  88*2=176B=11*16B;  44 dwords % 32 = 12

__global__ __launch_bounds__(256)
void attn_kernel(const bf16* __restrict__ Q, const bf16* __restrict__ K,
                 const bf16* __restrict__ Vt, bf16* __restrict__ ctx)
{
    const int qb = blockIdx.x;   // 0..31
    const int bh = blockIdx.y;   // 0..31
    const int tid = threadIdx.x;
    const int wave = tid >> 6, lane = tid & 63, quad = lane >> 4, l16 = lane & 15;

    __shared__ bf16 Qs[64][QKPAD];
    __shared__ bf16 Ks[64][QKPAD];
    __shared__ bf16 VsT[128][VPAD];     // [d][key]
    __shared__ bf16 Ps[4][16][VPAD];    // per-wave P, [m][key]

    // stage Q tile (64 rows x 128)
    const bf16* qsrc = Q + ((size_t)bh * SEQ + qb * 64) * DH;
#pragma unroll
    for (int i = 0; i < 4; ++i) {
        int idx = tid + i * 256;
        int row = idx >> 4, c = (idx & 15) * 8;
        *(bf16x8*)&Qs[row][c] = *(const bf16x8*)&qsrc[row * DH + c];
    }
    __syncthreads();

    // hoist Q fragments (constant across kb)
    bf16x8 qf[4];
#pragma unroll
    for (int dd = 0; dd < 4; ++dd)
        qf[dd] = *(const bf16x8*)&Qs[wave * 16 + l16][dd * 32 + quad * 8];

    f32x4 o[8] = {};
    float m_i[4], l_i[4];
#pragma unroll
    for (int r = 0; r < 4; ++r) { m_i[r] = -INFINITY; l_i[r] = 0.f; }

    const float scale = 0.08838834764831845f;  // 1/sqrt(128)
    const bf16* ksrc0 = K + (size_t)bh * SEQ * DH;
    const bf16* vsrc0 = Vt + (size_t)bh * DH * SEQ;

    for (int kb = 0; kb <= qb; ++kb) {
        __syncthreads();   // previous iteration's reads done
        // stage K tile (64 x 128)
        const bf16* ksrc = ksrc0 + (size_t)(kb * 64) * DH;
#pragma unroll
        for (int i = 0; i < 4; ++i) {
            int idx = tid + i * 256;
            int row = idx >> 4, c = (idx & 15) * 8;
            *(bf16x8*)&Ks[row][c] = *(const bf16x8*)&ksrc[row * DH + c];
        }
        // stage Vt tile (128 d-rows x 64 keys)
        const bf16* vsrc = vsrc0 + kb * 64;
#pragma unroll
        for (int i = 0; i < 4; ++i) {
            int idx = tid + i * 256;
            int d = idx >> 3, c = (idx & 7) * 8;
            *(bf16x8*)&VsT[d][c] = *(const bf16x8*)&vsrc[(size_t)d * SEQ + c];
        }
        __syncthreads();

        // S = Q K^T (16 rows x 64 keys per wave)
        f32x4 sc[4];
#pragma unroll
        for (int t = 0; t < 4; ++t) {
            f32x4 s = {};
#pragma unroll
            for (int dd = 0; dd < 4; ++dd) {
                bf16x8 b = *(const bf16x8*)&Ks[t * 16 + l16][dd * 32 + quad * 8];
                s = __builtin_amdgcn_mfma_f32_16x16x32_bf16(qf[dd], b, s, 0, 0, 0);
            }
            sc[t] = s;
        }

        const bool diag = (kb == qb);
        float pvals[4][4];
#pragma unroll
        for (int r = 0; r < 4; ++r) {
            int qrow = qb * 64 + wave * 16 + quad * 4 + r;
            float mx = -INFINITY;
#pragma unroll
            for (int t = 0; t < 4; ++t) {
                float s = sc[t][r] * scale;
                int kcol = kb * 64 + t * 16 + l16;
                if (diag && kcol > qrow) s = -INFINITY;
                pvals[t][r] = s;
                mx = fmaxf(mx, s);
            }
#pragma unroll
            for (int off = 1; off < 16; off <<= 1)
                mx = fmaxf(mx, __shfl_xor(mx, off, 64));
            float mnew = fmaxf(m_i[r], mx);
            float alpha = __expf(m_i[r] - mnew);
            m_i[r] = mnew;
            float rs = 0.f;
#pragma unroll
            for (int t = 0; t < 4; ++t) {
                float p = __expf(pvals[t][r] - mnew);
                pvals[t][r] = p;
                rs += p;
            }
#pragma unroll
            for (int off = 1; off < 16; off <<= 1)
                rs += __shfl_xor(rs, off, 64);
            l_i[r] = l_i[r] * alpha + rs;
#pragma unroll
            for (int dt = 0; dt < 8; ++dt) o[dt][r] *= alpha;
        }

        // P -> LDS (C-layout -> A-layout), wave-local
#pragma unroll
        for (int t = 0; t < 4; ++t)
#pragma unroll
            for (int r = 0; r < 4; ++r)
                Ps[wave][quad * 4 + r][t * 16 + l16] = (bf16)pvals[t][r];

        // O += P @ V  (vectorized b-fragments from VsT)
        bf16x8 pa[2];
#pragma unroll
        for (int kk2 = 0; kk2 < 2; ++kk2)
            pa[kk2] = *(const bf16x8*)&Ps[wave][l16][kk2 * 32 + quad * 8];
#pragma unroll
        for (int dt = 0; dt < 8; ++dt) {
#pragma unroll
            for (int kk2 = 0; kk2 < 2; ++kk2) {
                bf16x8 b = *(const bf16x8*)&VsT[dt * 16 + l16][kk2 * 32 + quad * 8];
                o[dt] = __builtin_amdgcn_mfma_f32_16x16x32_bf16(pa[kk2], b, o[dt], 0, 0, 0);
            }
        }
    }

    // epilogue
    const int b = bh >> 4, h = bh & (NHEADS - 1);
    float inv_l[4];
#pragma unroll
    for (int r = 0; r < 4; ++r) inv_l[r] = 1.0f / l_i[r];
#pragma unroll
    for (int dt = 0; dt < 8; ++dt) {
#pragma unroll
        for (int r = 0; r < 4; ++r) {
            int s = qb * 64 + wave * 16 + quad * 4 + r;
            int d = dt * 16 + l16;
            ctx[((size_t)(b * SEQ + s)) * D_MODEL + h * DH + d] = (bf16)(o[dt][r] * inv_l[r]);
        }
    }
}

// ---------------------------------------------------------------------------
// Residual + LayerNorm: one block per row
// ---------------------------------------------------------------------------
__global__ __launch_bounds__(256)
void ln_kernel(const float* __restrict__ attn, const float* __restrict__ x,
               const float* __restrict__ gamma, const float* __restrict__ beta,
               float* __restrict__ ln)
{
    const int row = blockIdx.x;
    const int tid = threadIdx.x;
    const int wave = tid >> 6, lane = tid & 63;
    const float* a  = attn + (size_t)row * D_MODEL;
    const float* xr = x    + (size_t)row * D_MODEL;

    float4 y4[2];
    float sum = 0.f, sumsq = 0.f;
#pragma unroll
    for (int i = 0; i < 2; ++i) {
        int c = (tid + i * 256) * 4;
        float4 av = *(const float4*)&a[c];
        float4 xv = *(const float4*)&xr[c];
        float4 y;
        y.x = av.x + xv.x; y.y = av.y + xv.y; y.z = av.z + xv.z; y.w = av.w + xv.w;
        y4[i] = y;
        sum   += y.x + y.y + y.z + y.w;
        sumsq += y.x * y.x + y.y * y.y + y.z * y.z + y.w * y.w;
    }
#pragma unroll
    for (int off = 1; off < 64; off <<= 1) {
        sum   += __shfl_xor(sum, off, 64);
        sumsq += __shfl_xor(sumsq, off, 64);
    }
    __shared__ float rsum[4], rsumsq[4];
    if (lane == 0) { rsum[wave] = sum; rsumsq[wave] = sumsq; }
    __syncthreads();
    float tot = 0.f, tot2 = 0.f;
#pragma unroll
    for (int i = 0; i < 4; ++i) { tot += rsum[i]; tot2 += rsumsq[i]; }
    const float mu  = tot * (1.0f / D_MODEL);
    const float var = tot2 * (1.0f / D_MODEL) - mu * mu;
    const float rstd = rsqrtf(var + 1e-5f);

#pragma unroll
    for (int i = 0; i < 2; ++i) {
        int c = (tid + i * 256) * 4;
        float4 gv = *(const float4*)&gamma[c];
        float4 bv = *(const float4*)&beta[c];
        float4 y = y4[i];
        float4 r;
        r.x = gv.x * (y.x - mu) * rstd + bv.x;
        r.y = gv.y * (y.y - mu) * rstd + bv.y;
        r.z = gv.z * (y.z - mu) * rstd + bv.z;
        r.w = gv.w * (y.w - mu) * rstd + bv.w;
        *(float4*)&ln[(size_t)row * D_MODEL + c] = r;
    }
}

// ---------------------------------------------------------------------------
extern "C" void kernel_launch(void* const* d_in, const int* in_sizes, int n_in,
                              void* d_out, int out_size, void* d_ws, size_t ws_size,
                              hipStream_t stream)
{
    const float* x     = (const float*)d_in[0];
    const float* Wq    = (const float*)d_in[1];
    const float* bq    = (const float*)d_in[2];
    const float* Wk    = (const float*)d_in[3];
    const float* bk    = (const float*)d_in[4];
    const float* Wv    = (const float*)d_in[5];
    const float* bv    = (const float*)d_in[6];
    const float* Wo    = (const float*)d_in[7];
    const float* bo    = (const float*)d_in[8];
    const float* gamma = (const float*)d_in[9];
    const float* beta  = (const float*)d_in[10];

    float* out      = (float*)d_out;
    float* ln       = out;                 // [B,S,D]
    float* attn_out = out + 8388608;       // [B,S,D]
    float* kout     = out + 16777216;      // [B,H,S,Dh]
    float* vout     = out + 25165824;      // [B,H,S,Dh]

    // workspace layout (bf16 elements)
    bf16* wsb  = (bf16*)d_ws;
    bf16* xb   = wsb;                        // [4096][2048]            8M
    bf16* WT   = wsb + 8388608;              // 4x [2048][2048] (q,k,v,o) 16M
    bf16* qws  = wsb + 25165824;             // [bh][s][128]            8M
    bf16* kb16 = wsb + 33554432;             // [bh][s][128]            8M
    bf16* vT   = wsb + 41943040;             // [bh][128][s]            8M
    bf16* ctx  = wsb + 50331648;             // [4096][2048]            8M

    convert_x_kernel<<<8192, 256, 0, stream>>>(x, xb);
    transpose_w_kernel<<<dim3(32, 32, 4), 256, 0, stream>>>(Wq, Wk, Wv, Wo, WT);
    gemm_qkv_kernel<<<dim3(16, 32, 3), 256, 0, stream>>>(xb, WT, bq, bk, bv,
                                                          qws, kout, kb16, vout);
    transpose_v_kernel<<<dim3(32, 2, 32), 256, 0, stream>>>(vout, vT);
    attn_kernel<<<dim3(32, 32), 256, 0, stream>>>(qws, kb16, vT, ctx);
    gemm_out_kernel<<<dim3(16, 32), 256, 0, stream>>>(ctx, WT + 3 * (size_t)(D_MODEL * D_MODEL),
                                                       bo, attn_out);
    ln_kernel<<<4096, 256, 0, stream>>>(attn_out, x, gamma, beta, ln);
}